// Round 5
// baseline (7696.832 us; speedup 1.0000x reference)
//
#include <hip/hip_runtime.h>
#include <hip/hip_bf16.h>

#define TT 12
#define HD 128
#define G3 384
#define LL 3
#define RW 32                 // rows per workgroup
#define NWG 2048              // 2048 * 32 = 65536 rows

typedef short bf16x8 __attribute__((ext_vector_type(8)));
typedef float f32x4 __attribute__((ext_vector_type(4)));
typedef unsigned short u16;

__device__ __forceinline__ float b2f(u16 u) {
  union { unsigned int i; float f; } c; c.i = ((unsigned int)u) << 16; return c.f;
}
__device__ __forceinline__ u16 f2b(float f) {
  __hip_bfloat16 h = __float2bfloat16(f);
  union { __hip_bfloat16 h; u16 u; } c; c.h = h; return c.u;
}
__device__ __forceinline__ float fsigm(float x) { return 1.f / (1.f + __expf(-x)); }
__device__ __forceinline__ float ftanh(float x) { return 1.f - 2.f / (__expf(2.f * x) + 1.f); }

// element-index swizzle inside a [RW][128] bf16 plane: XOR row into the
// 16B-granule index -> stride-256B column reads become conflict-free.
__device__ __forceinline__ int swz(int row, int k) {
  return (row << 7) + ((((k >> 3) ^ (row & 7))) << 3) + (k & 7);
}

__global__ __launch_bounds__(256) void cvt_kernel(const float* __restrict__ s,
                                                  u16* __restrict__ d, int n) {
  int i = blockIdx.x * 256 + threadIdx.x;
  if (i < n) d[i] = f2b(s[i]);
}

// ---------------------------------------------------------------------------
// GRU cell on LDS-resident activations. Wave = 16 units, 2 M-tiles of 16 rows.
// XLO: input slot has a lo-plane. ZH: hold is all-zero (skip h-MFMAs, in-place).
// Biases folded into accumulator init.
// ---------------------------------------------------------------------------
template <int XLO, int ZH>
__device__ __forceinline__ void gru_cell(
    u16 (*sHi)[RW * HD], u16 (*sLo)[RW * HD],
    int bin, int bhold, int bout, int wv, int lane,
    const u16* __restrict__ Wi, const u16* __restrict__ Wh,
    const float* __restrict__ bih, const float* __restrict__ bhh) {
  const int col = lane & 15, kg = lane >> 4;
  const int u = wv * 16 + col;

  bf16x8 wfi[3][4], wfh[3][4];
#pragma unroll
  for (int g = 0; g < 3; ++g)
#pragma unroll
    for (int kf = 0; kf < 4; ++kf) {
      int off = (g * 128 + u) * 128 + kf * 32 + kg * 8;
      wfi[g][kf] = *reinterpret_cast<const bf16x8*>(Wi + off);
      if (!ZH) wfh[g][kf] = *reinterpret_cast<const bf16x8*>(Wh + off);
    }
  const float br = bih[u] + bhh[u];
  const float bz = bih[128 + u] + bhh[128 + u];
  const float bni = bih[256 + u], bnh = bhh[256 + u];

  const u16* inH = sHi[bin];
  const u16* inL = XLO ? sLo[bin - 1] : (const u16*)nullptr;
  const u16* hoH = sHi[bhold];
  const u16* hoL = sLo[bhold - 1];
  u16* oH = sHi[bout];
  u16* oL = sLo[bout - 1];

#pragma unroll 1
  for (int mt = 0; mt < 2; ++mt) {
    const int r0 = mt * 16;
    const int arow = r0 + col;
    f32x4 ar = {br, br, br, br};
    f32x4 az = {bz, bz, bz, bz};
    f32x4 anx = {bni, bni, bni, bni};
    f32x4 anh = {bnh, bnh, bnh, bnh};
#pragma unroll
    for (int kf = 0; kf < 4; ++kf) {
      int off = swz(arow, kf * 32 + kg * 8);
      bf16x8 a_xh = *reinterpret_cast<const bf16x8*>(inH + off);
      ar = __builtin_amdgcn_mfma_f32_16x16x32_bf16(a_xh, wfi[0][kf], ar, 0, 0, 0);
      az = __builtin_amdgcn_mfma_f32_16x16x32_bf16(a_xh, wfi[1][kf], az, 0, 0, 0);
      anx = __builtin_amdgcn_mfma_f32_16x16x32_bf16(a_xh, wfi[2][kf], anx, 0, 0, 0);
      if (XLO) {
        bf16x8 a_xl = *reinterpret_cast<const bf16x8*>(inL + off);
        ar = __builtin_amdgcn_mfma_f32_16x16x32_bf16(a_xl, wfi[0][kf], ar, 0, 0, 0);
        az = __builtin_amdgcn_mfma_f32_16x16x32_bf16(a_xl, wfi[1][kf], az, 0, 0, 0);
        anx = __builtin_amdgcn_mfma_f32_16x16x32_bf16(a_xl, wfi[2][kf], anx, 0, 0, 0);
      }
      if (!ZH) {
        bf16x8 a_hh = *reinterpret_cast<const bf16x8*>(hoH + off);
        ar = __builtin_amdgcn_mfma_f32_16x16x32_bf16(a_hh, wfh[0][kf], ar, 0, 0, 0);
        az = __builtin_amdgcn_mfma_f32_16x16x32_bf16(a_hh, wfh[1][kf], az, 0, 0, 0);
        anh = __builtin_amdgcn_mfma_f32_16x16x32_bf16(a_hh, wfh[2][kf], anh, 0, 0, 0);
        bf16x8 a_hl = *reinterpret_cast<const bf16x8*>(hoL + off);
        ar = __builtin_amdgcn_mfma_f32_16x16x32_bf16(a_hl, wfh[0][kf], ar, 0, 0, 0);
        az = __builtin_amdgcn_mfma_f32_16x16x32_bf16(a_hl, wfh[1][kf], az, 0, 0, 0);
        anh = __builtin_amdgcn_mfma_f32_16x16x32_bf16(a_hl, wfh[2][kf], anh, 0, 0, 0);
      }
    }
#pragma unroll
    for (int v = 0; v < 4; ++v) {
      int row = r0 + kg * 4 + v;
      int idx = swz(row, u);
      float hp = ZH ? 0.f : (b2f(hoH[idx]) + b2f(hoL[idx]));
      float rg = fsigm(ar[v]);
      float zg = fsigm(az[v]);
      float ng = ftanh(anx[v] + rg * anh[v]);
      float hn = (1.f - zg) * ng + zg * hp;
      u16 hb = f2b(hn);
      oH[idx] = hb;
      oL[idx] = f2b(hn - b2f(hb));
    }
  }
}

// ---------------------------------------------------------------------------
template <int RELU, int XLO, int OUTLO>
__device__ __forceinline__ void lin128(
    u16 (*sHi)[RW * HD], u16 (*sLo)[RW * HD],
    int bin, int bout, int wv, int lane,
    const u16* __restrict__ W, const float* __restrict__ bias) {
  const int col = lane & 15, kg = lane >> 4;
  const int u = wv * 16 + col;
  bf16x8 wf[4];
#pragma unroll
  for (int kf = 0; kf < 4; ++kf)
    wf[kf] = *reinterpret_cast<const bf16x8*>(W + u * 128 + kf * 32 + kg * 8);
  const float bv = bias[u];
  const u16* inH = sHi[bin];
  const u16* inL = XLO ? sLo[bin - 1] : (const u16*)nullptr;
  u16* oH = sHi[bout];
  u16* oL = OUTLO ? sLo[bout - 1] : (u16*)nullptr;

#pragma unroll 1
  for (int mt = 0; mt < 2; ++mt) {
    const int r0 = mt * 16;
    const int arow = r0 + col;
    f32x4 acc = {bv, bv, bv, bv};
#pragma unroll
    for (int kf = 0; kf < 4; ++kf) {
      int off = swz(arow, kf * 32 + kg * 8);
      bf16x8 ah = *reinterpret_cast<const bf16x8*>(inH + off);
      acc = __builtin_amdgcn_mfma_f32_16x16x32_bf16(ah, wf[kf], acc, 0, 0, 0);
      if (XLO) {
        bf16x8 al = *reinterpret_cast<const bf16x8*>(inL + off);
        acc = __builtin_amdgcn_mfma_f32_16x16x32_bf16(al, wf[kf], acc, 0, 0, 0);
      }
    }
#pragma unroll
    for (int v = 0; v < 4; ++v) {
      int row = r0 + kg * 4 + v;
      int idx = swz(row, u);
      float val = acc[v];
      if (RELU) val = val > 0.f ? val : 0.f;
      u16 hb = f2b(val);
      oH[idx] = hb;
      if (OUTLO) oL[idx] = f2b(val - b2f(hb));
    }
  }
}

// ---------------------------------------------------------------------------
__global__ __launch_bounds__(512, 4) void mega_kernel(
    const float* __restrict__ x_true, float* __restrict__ out,
    const u16* __restrict__ eWi, const u16* __restrict__ eWh,
    const float* __restrict__ ebi, const float* __restrict__ ebh,
    const u16* __restrict__ eWt, const float* __restrict__ ebt,
    const u16* __restrict__ dWin, const float* __restrict__ dbin,
    const u16* __restrict__ dWi, const u16* __restrict__ dWh,
    const float* __restrict__ dbi, const float* __restrict__ dbh,
    const float* __restrict__ Wemb, const float* __restrict__ bemb,
    const float* __restrict__ Wout, const float* __restrict__ bout) {
  __shared__ __align__(16) u16 sHi[5][RW * HD];  // slot 0 = x (hi only), 1..4 = h
  __shared__ __align__(16) u16 sLo[4][RW * HD];  // lo planes for slots 1..4

  const int tid = threadIdx.x;
  const int wv = tid >> 6, lane = tid & 63;
  const int grow0 = blockIdx.x * RW;

  int s0 = 1, s1 = 2, s2 = 3, fr = 4;

  // ---------------- Encoder ----------------
#pragma unroll 1
  for (int t = 1; t <= TT - 2; ++t) {
    {  // embed -> slot 0 (hi only)
      int r = tid >> 4, e0 = (tid & 15) * 8;
      int grow = grow0 + r;
      float x0 = x_true[(grow * TT + t) * 2];
      float x1 = x_true[(grow * TT + t) * 2 + 1];
      bf16x8 vh;
#pragma unroll
      for (int j = 0; j < 8; ++j) {
        int e = e0 + j;
        float v = x0 * Wemb[2 * e] + x1 * Wemb[2 * e + 1] + bemb[e];
        vh[j] = (short)f2b(v > 0.f ? v : 0.f);
      }
      *reinterpret_cast<bf16x8*>(&sHi[0][swz(r, e0)]) = vh;
    }
    __syncthreads();
    if (t == 1) {  // zero hold: in-place writes, no rotation
      gru_cell<0, 1>(sHi, sLo, 0, s0, s0, wv, lane, eWi, eWh, ebi, ebh);
      __syncthreads();
      gru_cell<1, 1>(sHi, sLo, s0, s1, s1, wv, lane, eWi + G3 * HD, eWh + G3 * HD,
                     ebi + G3, ebh + G3);
      __syncthreads();
      gru_cell<1, 1>(sHi, sLo, s1, s2, s2, wv, lane, eWi + 2 * G3 * HD,
                     eWh + 2 * G3 * HD, ebi + 2 * G3, ebh + 2 * G3);
      __syncthreads();
    } else {
      gru_cell<0, 0>(sHi, sLo, 0, s0, fr, wv, lane, eWi, eWh, ebi, ebh);
      __syncthreads();
      { int o = s0; s0 = fr; fr = o; }
      gru_cell<1, 0>(sHi, sLo, s0, s1, fr, wv, lane, eWi + G3 * HD, eWh + G3 * HD,
                     ebi + G3, ebh + G3);
      __syncthreads();
      { int o = s1; s1 = fr; fr = o; }
      gru_cell<1, 0>(sHi, sLo, s1, s2, fr, wv, lane, eWi + 2 * G3 * HD,
                     eWh + 2 * G3 * HD, ebi + 2 * G3, ebh + 2 * G3);
      __syncthreads();
      { int o = s2; s2 = fr; fr = o; }
    }
  }

  // rep = h2 @ Wt^T + bt  -> fr (hi+lo)
  lin128<0, 1, 1>(sHi, sLo, s2, fr, wv, lane, eWt, ebt);
  __syncthreads();

  // ---------------- Decoder ----------------
#pragma unroll 1
  for (int st = 0; st < TT; ++st) {
    // r = relu(carry @ Win + bin) -> slot 0 (hi only)
    lin128<1, 1, 0>(sHi, sLo, st == 0 ? fr : s2, 0, wv, lane, dWin, dbin);
    __syncthreads();
    if (st == 0) {  // zero hold
      gru_cell<0, 1>(sHi, sLo, 0, s0, s0, wv, lane, dWi, dWh, dbi, dbh);
      __syncthreads();
      gru_cell<1, 1>(sHi, sLo, s0, s1, s1, wv, lane, dWi + G3 * HD, dWh + G3 * HD,
                     dbi + G3, dbh + G3);
      __syncthreads();
      gru_cell<1, 1>(sHi, sLo, s1, s2, s2, wv, lane, dWi + 2 * G3 * HD,
                     dWh + 2 * G3 * HD, dbi + 2 * G3, dbh + 2 * G3);
      __syncthreads();
    } else {
      gru_cell<0, 0>(sHi, sLo, 0, s0, fr, wv, lane, dWi, dWh, dbi, dbh);
      __syncthreads();
      { int o = s0; s0 = fr; fr = o; }
      gru_cell<1, 0>(sHi, sLo, s0, s1, fr, wv, lane, dWi + G3 * HD, dWh + G3 * HD,
                     dbi + G3, dbh + G3);
      __syncthreads();
      { int o = s1; s1 = fr; fr = o; }
      gru_cell<1, 0>(sHi, sLo, s1, s2, fr, wv, lane, dWi + 2 * G3 * HD,
                     dWh + 2 * G3 * HD, dbi + 2 * G3, dbh + 2 * G3);
      __syncthreads();
      { int o = s2; s2 = fr; fr = o; }
    }
    {  // y projection from s2: 16 threads per row, 8 k each
      int r = tid >> 4, kc = tid & 15;
      int grow = grow0 + r;
      int off = swz(r, kc * 8);
      bf16x8 vh = *reinterpret_cast<const bf16x8*>(&sHi[s2][off]);
      bf16x8 vl = *reinterpret_cast<const bf16x8*>(&sLo[s2 - 1][off]);
      float a0 = 0.f, a1 = 0.f;
#pragma unroll
      for (int j = 0; j < 8; ++j) {
        float hv = b2f((u16)vh[j]) + b2f((u16)vl[j]);
        a0 += hv * Wout[kc * 8 + j];
        a1 += hv * Wout[128 + kc * 8 + j];
      }
      a0 += __shfl_xor(a0, 1); a0 += __shfl_xor(a0, 2);
      a0 += __shfl_xor(a0, 4); a0 += __shfl_xor(a0, 8);
      a1 += __shfl_xor(a1, 1); a1 += __shfl_xor(a1, 2);
      a1 += __shfl_xor(a1, 4); a1 += __shfl_xor(a1, 8);
      if (kc == 0) {
        float2 y; y.x = a0 + bout[0]; y.y = a1 + bout[1];
        *reinterpret_cast<float2*>(&out[(grow * TT + st) * 2]) = y;
      }
    }
    // no barrier needed: next lin reads s2 (read-only overlap), writes slot 0
  }
}

// ---------------------------------------------------------------------------
extern "C" void kernel_launch(void* const* d_in, const int* in_sizes, int n_in,
                              void* d_out, int out_size, void* d_ws, size_t ws_size,
                              hipStream_t stream) {
  const float* x_true   = (const float*)d_in[0];
  const float* enc_Wemb = (const float*)d_in[1];
  const float* enc_bemb = (const float*)d_in[2];
  const float* enc_Wih  = (const float*)d_in[3];
  const float* enc_Whh  = (const float*)d_in[4];
  const float* enc_bih  = (const float*)d_in[5];
  const float* enc_bhh  = (const float*)d_in[6];
  const float* enc_Wt   = (const float*)d_in[7];
  const float* enc_bt   = (const float*)d_in[8];
  const float* dec_Win  = (const float*)d_in[9];
  const float* dec_bin  = (const float*)d_in[10];
  const float* dec_Wih  = (const float*)d_in[11];
  const float* dec_Whh  = (const float*)d_in[12];
  const float* dec_bih  = (const float*)d_in[13];
  const float* dec_bhh  = (const float*)d_in[14];
  const float* dec_Wout = (const float*)d_in[15];
  const float* dec_bout = (const float*)d_in[16];
  float* out = (float*)d_out;

  u16* wsB = (u16*)d_ws;
  const int WC = G3 * HD;
  u16* encWiB = wsB;
  u16* encWhB = encWiB + 3 * WC;
  u16* decWiB = encWhB + 3 * WC;
  u16* decWhB = decWiB + 3 * WC;
  u16* eWtB   = decWhB + 3 * WC;
  u16* dWinB  = eWtB + HD * HD;

  cvt_kernel<<<(3 * WC + 255) / 256, 256, 0, stream>>>(enc_Wih, encWiB, 3 * WC);
  cvt_kernel<<<(3 * WC + 255) / 256, 256, 0, stream>>>(enc_Whh, encWhB, 3 * WC);
  cvt_kernel<<<(3 * WC + 255) / 256, 256, 0, stream>>>(dec_Wih, decWiB, 3 * WC);
  cvt_kernel<<<(3 * WC + 255) / 256, 256, 0, stream>>>(dec_Whh, decWhB, 3 * WC);
  cvt_kernel<<<(HD * HD + 255) / 256, 256, 0, stream>>>(enc_Wt, eWtB, HD * HD);
  cvt_kernel<<<(HD * HD + 255) / 256, 256, 0, stream>>>(dec_Win, dWinB, HD * HD);

  mega_kernel<<<NWG, 512, 0, stream>>>(
      x_true, out,
      encWiB, encWhB, enc_bih, enc_bhh, eWtB, enc_bt,
      dWinB, dec_bin, decWiB, decWhB, dec_bih, dec_bhh,
      enc_Wemb, enc_bemb, dec_Wout, dec_bout);
}

// Round 6
// 3782.250 us; speedup vs baseline: 2.0350x; 2.0350x over previous
//
#include <hip/hip_runtime.h>
#include <hip/hip_bf16.h>

#define TT 12
#define HD 128
#define G3 384
#define LL 3
#define RW 64                 // rows per workgroup
#define NWG 1024              // 1024 * 64 = 65536 rows

typedef short bf16x8 __attribute__((ext_vector_type(8)));
typedef float f32x4 __attribute__((ext_vector_type(4)));
typedef unsigned short u16;

__device__ __forceinline__ float b2f(u16 u) {
  union { unsigned int i; float f; } c; c.i = ((unsigned int)u) << 16; return c.f;
}
__device__ __forceinline__ u16 f2b(float f) {
  __hip_bfloat16 h = __float2bfloat16(f);
  union { __hip_bfloat16 h; u16 u; } c; c.h = h; return c.u;
}
__device__ __forceinline__ float fsigm(float x) { return 1.f / (1.f + __expf(-x)); }
__device__ __forceinline__ float ftanh(float x) { return 1.f - 2.f / (__expf(2.f * x) + 1.f); }

// element-index swizzle inside a [RW][128] bf16 plane: XOR (row&7) into the
// 16B-granule index -> stride-256B column reads stay <=2-way banked.
__device__ __forceinline__ int swz(int row, int k) {
  return (row << 7) + ((((k >> 3) ^ (row & 7))) << 3) + (k & 7);
}

__global__ __launch_bounds__(256) void cvt_kernel(const float* __restrict__ s,
                                                  u16* __restrict__ d, int n) {
  int i = blockIdx.x * 256 + threadIdx.x;
  if (i < n) d[i] = f2b(s[i]);
}

// ---------------------------------------------------------------------------
// GRU cell on LDS-resident activations. Wave = 16 units, RW/16 M-tiles.
// XLO: input slot has a lo-plane. ZH: hold is all-zero (skip h-MFMAs, in-place).
// Weight frags (96 VGPR) loaded once, held across the whole mt loop.
// ---------------------------------------------------------------------------
template <int XLO, int ZH>
__device__ __forceinline__ void gru_cell(
    u16 (*sHi)[RW * HD], u16 (*sLo)[RW * HD],
    int bin, int bhold, int bout, int wv, int lane,
    const u16* __restrict__ Wi, const u16* __restrict__ Wh,
    const float* __restrict__ bih, const float* __restrict__ bhh) {
  const int col = lane & 15, kg = lane >> 4;
  const int u = wv * 16 + col;

  bf16x8 wfi[3][4], wfh[3][4];
#pragma unroll
  for (int g = 0; g < 3; ++g)
#pragma unroll
    for (int kf = 0; kf < 4; ++kf) {
      int off = (g * 128 + u) * 128 + kf * 32 + kg * 8;
      wfi[g][kf] = *reinterpret_cast<const bf16x8*>(Wi + off);
      if (!ZH) wfh[g][kf] = *reinterpret_cast<const bf16x8*>(Wh + off);
    }
  const float br = bih[u] + bhh[u];
  const float bz = bih[128 + u] + bhh[128 + u];
  const float bni = bih[256 + u], bnh = bhh[256 + u];

  const u16* inH = sHi[bin];
  const u16* inL = XLO ? sLo[bin - 1] : (const u16*)nullptr;
  const u16* hoH = sHi[bhold];
  const u16* hoL = sLo[bhold - 1];
  u16* oH = sHi[bout];
  u16* oL = sLo[bout - 1];

#pragma unroll 1
  for (int mt = 0; mt < RW / 16; ++mt) {
    const int r0 = mt * 16;
    const int arow = r0 + col;
    f32x4 ar = {br, br, br, br};
    f32x4 az = {bz, bz, bz, bz};
    f32x4 anx = {bni, bni, bni, bni};
    f32x4 anh = {bnh, bnh, bnh, bnh};
#pragma unroll
    for (int kf = 0; kf < 4; ++kf) {
      int off = swz(arow, kf * 32 + kg * 8);
      bf16x8 a_xh = *reinterpret_cast<const bf16x8*>(inH + off);
      ar = __builtin_amdgcn_mfma_f32_16x16x32_bf16(a_xh, wfi[0][kf], ar, 0, 0, 0);
      az = __builtin_amdgcn_mfma_f32_16x16x32_bf16(a_xh, wfi[1][kf], az, 0, 0, 0);
      anx = __builtin_amdgcn_mfma_f32_16x16x32_bf16(a_xh, wfi[2][kf], anx, 0, 0, 0);
      if (XLO) {
        bf16x8 a_xl = *reinterpret_cast<const bf16x8*>(inL + off);
        ar = __builtin_amdgcn_mfma_f32_16x16x32_bf16(a_xl, wfi[0][kf], ar, 0, 0, 0);
        az = __builtin_amdgcn_mfma_f32_16x16x32_bf16(a_xl, wfi[1][kf], az, 0, 0, 0);
        anx = __builtin_amdgcn_mfma_f32_16x16x32_bf16(a_xl, wfi[2][kf], anx, 0, 0, 0);
      }
      if (!ZH) {
        bf16x8 a_hh = *reinterpret_cast<const bf16x8*>(hoH + off);
        ar = __builtin_amdgcn_mfma_f32_16x16x32_bf16(a_hh, wfh[0][kf], ar, 0, 0, 0);
        az = __builtin_amdgcn_mfma_f32_16x16x32_bf16(a_hh, wfh[1][kf], az, 0, 0, 0);
        anh = __builtin_amdgcn_mfma_f32_16x16x32_bf16(a_hh, wfh[2][kf], anh, 0, 0, 0);
        bf16x8 a_hl = *reinterpret_cast<const bf16x8*>(hoL + off);
        ar = __builtin_amdgcn_mfma_f32_16x16x32_bf16(a_hl, wfh[0][kf], ar, 0, 0, 0);
        az = __builtin_amdgcn_mfma_f32_16x16x32_bf16(a_hl, wfh[1][kf], az, 0, 0, 0);
        anh = __builtin_amdgcn_mfma_f32_16x16x32_bf16(a_hl, wfh[2][kf], anh, 0, 0, 0);
      }
    }
#pragma unroll
    for (int v = 0; v < 4; ++v) {
      int row = r0 + kg * 4 + v;
      int idx = swz(row, u);
      float hp = ZH ? 0.f : (b2f(hoH[idx]) + b2f(hoL[idx]));
      float rg = fsigm(ar[v]);
      float zg = fsigm(az[v]);
      float ng = ftanh(anx[v] + rg * anh[v]);
      float hn = (1.f - zg) * ng + zg * hp;
      u16 hb = f2b(hn);
      oH[idx] = hb;
      oL[idx] = f2b(hn - b2f(hb));
    }
  }
}

// ---------------------------------------------------------------------------
template <int RELU, int XLO, int OUTLO>
__device__ __forceinline__ void lin128(
    u16 (*sHi)[RW * HD], u16 (*sLo)[RW * HD],
    int bin, int bout, int wv, int lane,
    const u16* __restrict__ W, const float* __restrict__ bias) {
  const int col = lane & 15, kg = lane >> 4;
  const int u = wv * 16 + col;
  bf16x8 wf[4];
#pragma unroll
  for (int kf = 0; kf < 4; ++kf)
    wf[kf] = *reinterpret_cast<const bf16x8*>(W + u * 128 + kf * 32 + kg * 8);
  const float bv = bias[u];
  const u16* inH = sHi[bin];
  const u16* inL = XLO ? sLo[bin - 1] : (const u16*)nullptr;
  u16* oH = sHi[bout];
  u16* oL = OUTLO ? sLo[bout - 1] : (u16*)nullptr;

#pragma unroll 1
  for (int mt = 0; mt < RW / 16; ++mt) {
    const int r0 = mt * 16;
    const int arow = r0 + col;
    f32x4 acc = {bv, bv, bv, bv};
#pragma unroll
    for (int kf = 0; kf < 4; ++kf) {
      int off = swz(arow, kf * 32 + kg * 8);
      bf16x8 ah = *reinterpret_cast<const bf16x8*>(inH + off);
      acc = __builtin_amdgcn_mfma_f32_16x16x32_bf16(ah, wf[kf], acc, 0, 0, 0);
      if (XLO) {
        bf16x8 al = *reinterpret_cast<const bf16x8*>(inL + off);
        acc = __builtin_amdgcn_mfma_f32_16x16x32_bf16(al, wf[kf], acc, 0, 0, 0);
      }
    }
#pragma unroll
    for (int v = 0; v < 4; ++v) {
      int row = r0 + kg * 4 + v;
      int idx = swz(row, u);
      float val = acc[v];
      if (RELU) val = val > 0.f ? val : 0.f;
      u16 hb = f2b(val);
      oH[idx] = hb;
      if (OUTLO) oL[idx] = f2b(val - b2f(hb));
    }
  }
}

// ---------------------------------------------------------------------------
__global__ __launch_bounds__(512, 2) void mega_kernel(
    const float* __restrict__ x_true, float* __restrict__ out,
    const u16* __restrict__ eWi, const u16* __restrict__ eWh,
    const float* __restrict__ ebi, const float* __restrict__ ebh,
    const u16* __restrict__ eWt, const float* __restrict__ ebt,
    const u16* __restrict__ dWin, const float* __restrict__ dbin,
    const u16* __restrict__ dWi, const u16* __restrict__ dWh,
    const float* __restrict__ dbi, const float* __restrict__ dbh,
    const float* __restrict__ Wemb, const float* __restrict__ bemb,
    const float* __restrict__ Wout, const float* __restrict__ bout) {
  __shared__ __align__(16) u16 sHi[5][RW * HD];  // slot 0 = x (hi only), 1..4 = h
  __shared__ __align__(16) u16 sLo[4][RW * HD];  // lo planes for slots 1..4

  const int tid = threadIdx.x;
  const int wv = tid >> 6, lane = tid & 63;
  const int grow0 = blockIdx.x * RW;

  int s0 = 1, s1 = 2, s2 = 3, fr = 4;

  // ---------------- Encoder ----------------
#pragma unroll 1
  for (int t = 1; t <= TT - 2; ++t) {
    {  // embed -> slot 0 (hi only): row = tid>>3, 16 elems per thread
      int r = tid >> 3, e0 = (tid & 7) * 16;
      int grow = grow0 + r;
      float x0 = x_true[(grow * TT + t) * 2];
      float x1 = x_true[(grow * TT + t) * 2 + 1];
#pragma unroll
      for (int half = 0; half < 2; ++half) {
        bf16x8 vh;
#pragma unroll
        for (int j = 0; j < 8; ++j) {
          int e = e0 + half * 8 + j;
          float v = x0 * Wemb[2 * e] + x1 * Wemb[2 * e + 1] + bemb[e];
          vh[j] = (short)f2b(v > 0.f ? v : 0.f);
        }
        *reinterpret_cast<bf16x8*>(&sHi[0][swz(r, e0 + half * 8)]) = vh;
      }
    }
    __syncthreads();
    if (t == 1) {  // zero hold: in-place writes, no rotation
      gru_cell<0, 1>(sHi, sLo, 0, s0, s0, wv, lane, eWi, eWh, ebi, ebh);
      __syncthreads();
      gru_cell<1, 1>(sHi, sLo, s0, s1, s1, wv, lane, eWi + G3 * HD, eWh + G3 * HD,
                     ebi + G3, ebh + G3);
      __syncthreads();
      gru_cell<1, 1>(sHi, sLo, s1, s2, s2, wv, lane, eWi + 2 * G3 * HD,
                     eWh + 2 * G3 * HD, ebi + 2 * G3, ebh + 2 * G3);
      __syncthreads();
    } else {
      gru_cell<0, 0>(sHi, sLo, 0, s0, fr, wv, lane, eWi, eWh, ebi, ebh);
      __syncthreads();
      { int o = s0; s0 = fr; fr = o; }
      gru_cell<1, 0>(sHi, sLo, s0, s1, fr, wv, lane, eWi + G3 * HD, eWh + G3 * HD,
                     ebi + G3, ebh + G3);
      __syncthreads();
      { int o = s1; s1 = fr; fr = o; }
      gru_cell<1, 0>(sHi, sLo, s1, s2, fr, wv, lane, eWi + 2 * G3 * HD,
                     eWh + 2 * G3 * HD, ebi + 2 * G3, ebh + 2 * G3);
      __syncthreads();
      { int o = s2; s2 = fr; fr = o; }
    }
  }

  // rep = h2 @ Wt^T + bt  -> fr (hi+lo)
  lin128<0, 1, 1>(sHi, sLo, s2, fr, wv, lane, eWt, ebt);
  __syncthreads();

  // ---------------- Decoder ----------------
#pragma unroll 1
  for (int st = 0; st < TT; ++st) {
    // r = relu(carry @ Win + bin) -> slot 0 (hi only)
    lin128<1, 1, 0>(sHi, sLo, st == 0 ? fr : s2, 0, wv, lane, dWin, dbin);
    __syncthreads();
    if (st == 0) {  // zero hold
      gru_cell<0, 1>(sHi, sLo, 0, s0, s0, wv, lane, dWi, dWh, dbi, dbh);
      __syncthreads();
      gru_cell<1, 1>(sHi, sLo, s0, s1, s1, wv, lane, dWi + G3 * HD, dWh + G3 * HD,
                     dbi + G3, dbh + G3);
      __syncthreads();
      gru_cell<1, 1>(sHi, sLo, s1, s2, s2, wv, lane, dWi + 2 * G3 * HD,
                     dWh + 2 * G3 * HD, dbi + 2 * G3, dbh + 2 * G3);
      __syncthreads();
    } else {
      gru_cell<0, 0>(sHi, sLo, 0, s0, fr, wv, lane, dWi, dWh, dbi, dbh);
      __syncthreads();
      { int o = s0; s0 = fr; fr = o; }
      gru_cell<1, 0>(sHi, sLo, s0, s1, fr, wv, lane, dWi + G3 * HD, dWh + G3 * HD,
                     dbi + G3, dbh + G3);
      __syncthreads();
      { int o = s1; s1 = fr; fr = o; }
      gru_cell<1, 0>(sHi, sLo, s1, s2, fr, wv, lane, dWi + 2 * G3 * HD,
                     dWh + 2 * G3 * HD, dbi + 2 * G3, dbh + 2 * G3);
      __syncthreads();
      { int o = s2; s2 = fr; fr = o; }
    }
    {  // y projection from s2: row = tid>>3, 16 k-elems per thread
      int r = tid >> 3, kc = tid & 7;
      int grow = grow0 + r;
      float a0 = 0.f, a1 = 0.f;
#pragma unroll
      for (int half = 0; half < 2; ++half) {
        int k0 = kc * 16 + half * 8;
        int off = swz(r, k0);
        bf16x8 vh = *reinterpret_cast<const bf16x8*>(&sHi[s2][off]);
        bf16x8 vl = *reinterpret_cast<const bf16x8*>(&sLo[s2 - 1][off]);
#pragma unroll
        for (int j = 0; j < 8; ++j) {
          float hv = b2f((u16)vh[j]) + b2f((u16)vl[j]);
          a0 += hv * Wout[k0 + j];
          a1 += hv * Wout[128 + k0 + j];
        }
      }
      a0 += __shfl_xor(a0, 1); a0 += __shfl_xor(a0, 2); a0 += __shfl_xor(a0, 4);
      a1 += __shfl_xor(a1, 1); a1 += __shfl_xor(a1, 2); a1 += __shfl_xor(a1, 4);
      if (kc == 0) {
        float2 y; y.x = a0 + bout[0]; y.y = a1 + bout[1];
        *reinterpret_cast<float2*>(&out[(grow * TT + st) * 2]) = y;
      }
    }
    // no barrier needed: next lin reads s2 (read-only overlap), writes slot 0
  }
}

// ---------------------------------------------------------------------------
extern "C" void kernel_launch(void* const* d_in, const int* in_sizes, int n_in,
                              void* d_out, int out_size, void* d_ws, size_t ws_size,
                              hipStream_t stream) {
  const float* x_true   = (const float*)d_in[0];
  const float* enc_Wemb = (const float*)d_in[1];
  const float* enc_bemb = (const float*)d_in[2];
  const float* enc_Wih  = (const float*)d_in[3];
  const float* enc_Whh  = (const float*)d_in[4];
  const float* enc_bih  = (const float*)d_in[5];
  const float* enc_bhh  = (const float*)d_in[6];
  const float* enc_Wt   = (const float*)d_in[7];
  const float* enc_bt   = (const float*)d_in[8];
  const float* dec_Win  = (const float*)d_in[9];
  const float* dec_bin  = (const float*)d_in[10];
  const float* dec_Wih  = (const float*)d_in[11];
  const float* dec_Whh  = (const float*)d_in[12];
  const float* dec_bih  = (const float*)d_in[13];
  const float* dec_bhh  = (const float*)d_in[14];
  const float* dec_Wout = (const float*)d_in[15];
  const float* dec_bout = (const float*)d_in[16];
  float* out = (float*)d_out;

  u16* wsB = (u16*)d_ws;
  const int WC = G3 * HD;
  u16* encWiB = wsB;
  u16* encWhB = encWiB + 3 * WC;
  u16* decWiB = encWhB + 3 * WC;
  u16* decWhB = decWiB + 3 * WC;
  u16* eWtB   = decWhB + 3 * WC;
  u16* dWinB  = eWtB + HD * HD;

  cvt_kernel<<<(3 * WC + 255) / 256, 256, 0, stream>>>(enc_Wih, encWiB, 3 * WC);
  cvt_kernel<<<(3 * WC + 255) / 256, 256, 0, stream>>>(enc_Whh, encWhB, 3 * WC);
  cvt_kernel<<<(3 * WC + 255) / 256, 256, 0, stream>>>(dec_Wih, decWiB, 3 * WC);
  cvt_kernel<<<(3 * WC + 255) / 256, 256, 0, stream>>>(dec_Whh, decWhB, 3 * WC);
  cvt_kernel<<<(HD * HD + 255) / 256, 256, 0, stream>>>(enc_Wt, eWtB, HD * HD);
  cvt_kernel<<<(HD * HD + 255) / 256, 256, 0, stream>>>(dec_Win, dWinB, HD * HD);

  mega_kernel<<<NWG, 512, 0, stream>>>(
      x_true, out,
      encWiB, encWhB, enc_bih, enc_bhh, eWtB, enc_bt,
      dWinB, dec_bin, decWiB, decWhB, dec_bih, dec_bhh,
      enc_Wemb, enc_bemb, dec_Wout, dec_bout);
}